// Round 1
// baseline (2519.091 us; speedup 1.0000x reference)
//
#include <hip/hip_runtime.h>

typedef short bf16x8 __attribute__((ext_vector_type(8)));
typedef float f32x4 __attribute__((ext_vector_type(4)));

#define S_LEN 2048
#define NHEAD 16
#define HSZ 128

__device__ __forceinline__ float bf2f(ushort u) {
    union { unsigned int i; float f; } x; x.i = ((unsigned int)u) << 16; return x.f;
}
__device__ __forceinline__ ushort f2bf(float f) {
    union { float f; unsigned int i; } x; x.f = f;
    unsigned int r = (x.i + 0x7FFFu + ((x.i >> 16) & 1u)) >> 16;
    return (ushort)r;
}

// ---------------- cast fp32 -> bf16 (vectorized) ----------------
__global__ void cast_kernel(const float* __restrict__ in, ushort* __restrict__ out, int n4) {
    int i = blockIdx.x * 256 + threadIdx.x;
    if (i >= n4) return;
    float4 v = ((const float4*)in)[i];
    ushort4 r;
    r.x = f2bf(v.x); r.y = f2bf(v.y); r.z = f2bf(v.z); r.w = f2bf(v.w);
    ((ushort4*)out)[i] = r;
}

// ---------------- transpose + cast: W[K][N] fp32 -> WT[N][K] bf16 ----------------
__global__ void transpose_cast(const float* __restrict__ W, ushort* __restrict__ WT,
                               int K, int N) {
    __shared__ float tile[32][33];
    int n = blockIdx.x * 32 + threadIdx.x;
    #pragma unroll
    for (int j = 0; j < 32; j += 8) {
        int k = blockIdx.y * 32 + threadIdx.y + j;
        tile[threadIdx.y + j][threadIdx.x] = W[(size_t)k * N + n];
    }
    __syncthreads();
    int k2 = blockIdx.y * 32 + threadIdx.x;
    #pragma unroll
    for (int j = 0; j < 32; j += 8) {
        int n2 = blockIdx.x * 32 + threadIdx.y + j;
        WT[(size_t)n2 * K + k2] = f2bf(tile[threadIdx.x][threadIdx.y + j]);
    }
}

// ---------------- 128x128 bf16 MFMA GEMM, Bt is [N][K] ----------------
// EPI 0: scatter into Q/K/V bf16 (B,H,S,HS) with bias
// EPI 1: fp32 out[m*Ndim+n] with bias
template <int EPI>
__global__ __launch_bounds__(256) void gemm128(
    const ushort* __restrict__ A, const ushort* __restrict__ Bt,
    const float* __restrict__ bias, float* __restrict__ Cout, int Kdim, int Ndim,
    ushort* __restrict__ q_out, ushort* __restrict__ k_out, ushort* __restrict__ v_out) {
    __shared__ __align__(16) ushort lA[128 * 32];
    __shared__ __align__(16) ushort lB[128 * 32];
    const int tid = threadIdx.x;
    const int m0 = blockIdx.y * 128, n0 = blockIdx.x * 128;
    const int lane = tid & 63, wid = tid >> 6;
    const int wm = wid >> 1, wn = wid & 1, lm = lane & 15, quad = lane >> 4;
    const int srow = tid >> 2, schunk = tid & 3;

    f32x4 acc[16];
    #pragma unroll
    for (int i = 0; i < 16; ++i) acc[i] = (f32x4){0.f, 0.f, 0.f, 0.f};

    for (int k0 = 0; k0 < Kdim; k0 += 32) {
        uint4 a0 = *(const uint4*)(A + (size_t)(m0 + srow) * Kdim + k0 + schunk * 8);
        uint4 a1 = *(const uint4*)(A + (size_t)(m0 + srow + 64) * Kdim + k0 + schunk * 8);
        uint4 b0 = *(const uint4*)(Bt + (size_t)(n0 + srow) * Kdim + k0 + schunk * 8);
        uint4 b1 = *(const uint4*)(Bt + (size_t)(n0 + srow + 64) * Kdim + k0 + schunk * 8);
        __syncthreads();
        ((uint4*)lA)[srow * 4 + schunk] = a0;
        ((uint4*)lA)[(srow + 64) * 4 + schunk] = a1;
        ((uint4*)lB)[srow * 4 + schunk] = b0;
        ((uint4*)lB)[(srow + 64) * 4 + schunk] = b1;
        __syncthreads();
        bf16x8 af[4], bfr[4];
        #pragma unroll
        for (int t = 0; t < 4; ++t) {
            af[t]  = *(const bf16x8*)(lA + (wm * 64 + t * 16 + lm) * 32 + quad * 8);
            bfr[t] = *(const bf16x8*)(lB + (wn * 64 + t * 16 + lm) * 32 + quad * 8);
        }
        #pragma unroll
        for (int mt = 0; mt < 4; ++mt)
            #pragma unroll
            for (int nt = 0; nt < 4; ++nt)
                acc[mt * 4 + nt] = __builtin_amdgcn_mfma_f32_16x16x32_bf16(
                    af[mt], bfr[nt], acc[mt * 4 + nt], 0, 0, 0);
    }

    #pragma unroll
    for (int mt = 0; mt < 4; ++mt) {
        #pragma unroll
        for (int nt = 0; nt < 4; ++nt) {
            f32x4 c = acc[mt * 4 + nt];
            int gn = n0 + wn * 64 + nt * 16 + lm;
            float bv = bias[gn];
            #pragma unroll
            for (int i = 0; i < 4; ++i) {
                int gm = m0 + wm * 64 + mt * 16 + quad * 4 + i;
                float v = c[i] + bv;
                if (EPI == 0) {
                    int h = gn / 384, r = gn - h * 384;
                    int t = r >> 7, d = r & 127;
                    int b = gm >> 11, s = gm & 2047;
                    size_t off = ((size_t)(b * NHEAD + h) * S_LEN + s) * HSZ + d;
                    ushort bb = f2bf(v);
                    if (t == 0) q_out[off] = bb;
                    else if (t == 1) k_out[off] = bb;
                    else v_out[off] = bb;
                } else {
                    Cout[(size_t)gm * Ndim + gn] = v;
                }
            }
        }
    }
}

// ---------------- RoPE in place on dims 0..31 of Q and K ----------------
__global__ void rope_kernel(ushort* __restrict__ Qr, ushort* __restrict__ Kr,
                            const int* __restrict__ pos_ids) {
    int idx = blockIdx.x * 256 + threadIdx.x;   // B*H*S*16 = 1048576
    int j = idx & 15;
    int row = idx >> 4;            // (b*16+h)*2048 + s
    int s = row & 2047;
    int bh = row >> 11;
    int b = bh >> 4;
    int pos = pos_ids[b * S_LEN + s];
    // inv_freq = 10000^(-j/16); angle computed in double to beat fp32 range issues
    double inv = exp2(-(double)j * (13.287712379549449 / 16.0));
    double th = (double)pos * inv;
    float c = (float)cos(th), sn = (float)sin(th);
    size_t base = (size_t)row * HSZ;
    {
        float x1 = bf2f(Qr[base + j]), x2 = bf2f(Qr[base + j + 16]);
        Qr[base + j]      = f2bf(x1 * c - x2 * sn);
        Qr[base + j + 16] = f2bf(x2 * c + x1 * sn);
    }
    {
        float x1 = bf2f(Kr[base + j]), x2 = bf2f(Kr[base + j + 16]);
        Kr[base + j]      = f2bf(x1 * c - x2 * sn);
        Kr[base + j + 16] = f2bf(x2 * c + x1 * sn);
    }
}

// ---------------- attention: block = (b,h, 32 q rows), online softmax ----------------
// LDS rows padded to 132 floats -> K/V inner-loop reads are conflict-free (8 distinct
// 16B addrs spanning all 32 banks, broadcast across the 8 lanes sharing a q row).
__global__ __launch_bounds__(256) void attn_kernel(
    const ushort* __restrict__ Q, const ushort* __restrict__ K,
    const ushort* __restrict__ V, ushort* __restrict__ O) {
    __shared__ __align__(16) float lQ[32 * 132];
    __shared__ __align__(16) float lK[32 * 132];
    __shared__ __align__(16) float lV[32 * 132];
    __shared__ __align__(16) float lP[32 * 40];
    const int tid = threadIdx.x;
    const int bh = blockIdx.y;
    const int q0 = blockIdx.x * 32;
    const size_t base = (size_t)bh * S_LEN * HSZ;
    const ushort* Qb = Q + base + (size_t)q0 * HSZ;
    const ushort* Kb = K + base;
    const ushort* Vb = V + base;

    // stage Q tile (32x128 bf16 -> fp32 LDS)
    #pragma unroll
    for (int p = 0; p < 2; ++p) {
        int e = tid + p * 256;          // uint4 index; row=e>>4, ch=e&15
        int row = e >> 4, ch = e & 15;
        uint4 raw = ((const uint4*)Qb)[e];
        const ushort* u = (const ushort*)&raw;
        float* dst = lQ + row * 132 + ch * 8;
        #pragma unroll
        for (int j = 0; j < 8; ++j) dst[j] = bf2f(u[j]);
    }

    const int qr = tid >> 3, tc = tid & 7;
    float m = -1e30f, l = 0.f;
    float o[16];
    #pragma unroll
    for (int j = 0; j < 16; ++j) o[j] = 0.f;
    const float scale = 0.08838834764831845f;  // 1/sqrt(128)

    for (int kt = 0; kt < S_LEN / 32; ++kt) {
        __syncthreads();   // protect lK/lV from previous iteration's readers
        #pragma unroll
        for (int p = 0; p < 2; ++p) {
            int e = tid + p * 256;
            int row = e >> 4, ch = e & 15;
            uint4 kraw = ((const uint4*)Kb)[kt * 512 + e];
            uint4 vraw = ((const uint4*)Vb)[kt * 512 + e];
            const ushort* ku = (const ushort*)&kraw;
            const ushort* vu = (const ushort*)&vraw;
            float* kd = lK + row * 132 + ch * 8;
            float* vd = lV + row * 132 + ch * 8;
            #pragma unroll
            for (int j = 0; j < 8; ++j) { kd[j] = bf2f(ku[j]); vd[j] = bf2f(vu[j]); }
        }
        __syncthreads();

        // scores: thread (qr, tc) does keys tc, tc+8, tc+16, tc+24
        float sarr[4] = {0.f, 0.f, 0.f, 0.f};
        for (int c = 0; c < 32; ++c) {
            float4 qv = *(const float4*)(lQ + qr * 132 + c * 4);
            #pragma unroll
            for (int kk = 0; kk < 4; ++kk) {
                float4 kv = *(const float4*)(lK + (tc + 8 * kk) * 132 + c * 4);
                sarr[kk] = fmaf(qv.x, kv.x, sarr[kk]);
                sarr[kk] = fmaf(qv.y, kv.y, sarr[kk]);
                sarr[kk] = fmaf(qv.z, kv.z, sarr[kk]);
                sarr[kk] = fmaf(qv.w, kv.w, sarr[kk]);
            }
        }
        float tmax = -1e30f;
        #pragma unroll
        for (int kk = 0; kk < 4; ++kk) { sarr[kk] *= scale; tmax = fmaxf(tmax, sarr[kk]); }
        #pragma unroll
        for (int off = 1; off < 8; off <<= 1) tmax = fmaxf(tmax, __shfl_xor(tmax, off));
        float mnew = fmaxf(m, tmax);
        float alpha = __expf(m - mnew);
        float psum = 0.f;
        #pragma unroll
        for (int kk = 0; kk < 4; ++kk) {
            float p = __expf(sarr[kk] - mnew);
            lP[qr * 40 + tc + 8 * kk] = p;   // stride 40: 2-way max on write, free
            psum += p;
        }
        #pragma unroll
        for (int off = 1; off < 8; off <<= 1) psum += __shfl_xor(psum, off);
        l = l * alpha + psum;
        m = mnew;
        #pragma unroll
        for (int j = 0; j < 16; ++j) o[j] *= alpha;

        // PV: thread owns dims {tc*4 + 32*jj + e}; same-wave lP producer/consumer
        for (int k = 0; k < 32; ++k) {
            float pv = lP[qr * 40 + k];
            #pragma unroll
            for (int jj = 0; jj < 4; ++jj) {
                float4 vv = *(const float4*)(lV + k * 132 + tc * 4 + 32 * jj);
                o[jj * 4 + 0] = fmaf(pv, vv.x, o[jj * 4 + 0]);
                o[jj * 4 + 1] = fmaf(pv, vv.y, o[jj * 4 + 1]);
                o[jj * 4 + 2] = fmaf(pv, vv.z, o[jj * 4 + 2]);
                o[jj * 4 + 3] = fmaf(pv, vv.w, o[jj * 4 + 3]);
            }
        }
    }

    float invl = 1.f / l;
    int b = bh >> 4, h = bh & 15;
    size_t orow = ((size_t)(b * S_LEN + q0 + qr) * (NHEAD * HSZ)) + h * HSZ;
    #pragma unroll
    for (int jj = 0; jj < 4; ++jj) {
        ushort4 pk;
        pk.x = f2bf(o[jj * 4 + 0] * invl);
        pk.y = f2bf(o[jj * 4 + 1] * invl);
        pk.z = f2bf(o[jj * 4 + 2] * invl);
        pk.w = f2bf(o[jj * 4 + 3] * invl);
        *(ushort4*)(O + orow + tc * 4 + 32 * jj) = pk;
    }
}

extern "C" void kernel_launch(void* const* d_in, const int* in_sizes, int n_in,
                              void* d_out, int out_size, void* d_ws, size_t ws_size,
                              hipStream_t stream) {
    const float* hidden = (const float*)d_in[0];
    const int*   pos    = (const int*)d_in[1];
    const float* Wqkv   = (const float*)d_in[2];
    const float* bqkv   = (const float*)d_in[3];
    const float* Wd     = (const float*)d_in[4];
    const float* bd     = (const float*)d_in[5];

    char* ws = (char*)d_ws;
    ushort* hA  = (ushort*)ws;                               // 16,777,216 B (reused as O)
    ushort* WqT = (ushort*)(ws + 16777216ull);               // 25,165,824 B
    ushort* WdT = (ushort*)(ws + 41943040ull);               //  8,388,608 B
    ushort* Qb  = (ushort*)(ws + 50331648ull);               // 16,777,216 B
    ushort* Kb  = (ushort*)(ws + 67108864ull);               // 16,777,216 B
    ushort* Vb  = (ushort*)(ws + 83886080ull);               // 16,777,216 B
    // total 100,663,296 B

    cast_kernel<<<dim3(8192), dim3(256), 0, stream>>>(hidden, hA, 2097152);
    transpose_cast<<<dim3(192, 64), dim3(32, 8), 0, stream>>>(Wqkv, WqT, 2048, 6144);
    transpose_cast<<<dim3(64, 64), dim3(32, 8), 0, stream>>>(Wd, WdT, 2048, 2048);

    gemm128<0><<<dim3(48, 32), dim3(256), 0, stream>>>(hA, WqT, bqkv, nullptr, 2048, 6144,
                                                       Qb, Kb, Vb);
    rope_kernel<<<dim3(4096), dim3(256), 0, stream>>>(Qb, Kb, pos);

    ushort* Obuf = hA;  // hidden bf16 no longer needed
    attn_kernel<<<dim3(64, 32), dim3(256), 0, stream>>>(Qb, Kb, Vb, Obuf);

    gemm128<1><<<dim3(16, 32), dim3(256), 0, stream>>>(Obuf, WdT, bd, (float*)d_out,
                                                       2048, 2048, nullptr, nullptr, nullptr);
}

// Round 2
// 475.508 us; speedup vs baseline: 5.2977x; 5.2977x over previous
//
#include <hip/hip_runtime.h>

typedef short bf16x8 __attribute__((ext_vector_type(8)));
typedef float f32x4 __attribute__((ext_vector_type(4)));

#define S_LEN 2048
#define NHEAD 16
#define HSZ 128

__device__ __forceinline__ float bf2f(ushort u) {
    union { unsigned int i; float f; } x; x.i = ((unsigned int)u) << 16; return x.f;
}
__device__ __forceinline__ ushort f2bf(float f) {
    union { float f; unsigned int i; } x; x.f = f;
    unsigned int r = (x.i + 0x7FFFu + ((x.i >> 16) & 1u)) >> 16;
    return (ushort)r;
}

// ---------------- cast fp32 -> bf16 (vectorized) ----------------
__global__ void cast_kernel(const float* __restrict__ in, ushort* __restrict__ out, int n4) {
    int i = blockIdx.x * 256 + threadIdx.x;
    if (i >= n4) return;
    float4 v = ((const float4*)in)[i];
    ushort4 r;
    r.x = f2bf(v.x); r.y = f2bf(v.y); r.z = f2bf(v.z); r.w = f2bf(v.w);
    ((ushort4*)out)[i] = r;
}

// ---------------- transpose + cast: W[K][N] fp32 -> WT[N][K] bf16 ----------------
__global__ void transpose_cast(const float* __restrict__ W, ushort* __restrict__ WT,
                               int K, int N) {
    __shared__ float tile[32][33];
    int n = blockIdx.x * 32 + threadIdx.x;
    #pragma unroll
    for (int j = 0; j < 32; j += 8) {
        int k = blockIdx.y * 32 + threadIdx.y + j;
        tile[threadIdx.y + j][threadIdx.x] = W[(size_t)k * N + n];
    }
    __syncthreads();
    int k2 = blockIdx.y * 32 + threadIdx.x;
    #pragma unroll
    for (int j = 0; j < 32; j += 8) {
        int n2 = blockIdx.x * 32 + threadIdx.y + j;
        WT[(size_t)n2 * K + k2] = f2bf(tile[threadIdx.x][threadIdx.y + j]);
    }
}

// ---------------- 128x128 bf16 MFMA GEMM, Bt is [N][K] ----------------
// EPI 0: scatter into Q/K bf16 (B,H,S,HS), V TRANSPOSED (B,H,HS,S), with bias
// EPI 1: fp32 out[m*Ndim+n] with bias
template <int EPI>
__global__ __launch_bounds__(256) void gemm128(
    const ushort* __restrict__ A, const ushort* __restrict__ Bt,
    const float* __restrict__ bias, float* __restrict__ Cout, int Kdim, int Ndim,
    ushort* __restrict__ q_out, ushort* __restrict__ k_out, ushort* __restrict__ v_out) {
    __shared__ __align__(16) ushort lA[128 * 32];
    __shared__ __align__(16) ushort lB[128 * 32];
    const int tid = threadIdx.x;
    const int m0 = blockIdx.y * 128, n0 = blockIdx.x * 128;
    const int lane = tid & 63, wid = tid >> 6;
    const int wm = wid >> 1, wn = wid & 1, lm = lane & 15, quad = lane >> 4;
    const int srow = tid >> 2, schunk = tid & 3;

    f32x4 acc[16];
    #pragma unroll
    for (int i = 0; i < 16; ++i) acc[i] = (f32x4){0.f, 0.f, 0.f, 0.f};

    for (int k0 = 0; k0 < Kdim; k0 += 32) {
        uint4 a0 = *(const uint4*)(A + (size_t)(m0 + srow) * Kdim + k0 + schunk * 8);
        uint4 a1 = *(const uint4*)(A + (size_t)(m0 + srow + 64) * Kdim + k0 + schunk * 8);
        uint4 b0 = *(const uint4*)(Bt + (size_t)(n0 + srow) * Kdim + k0 + schunk * 8);
        uint4 b1 = *(const uint4*)(Bt + (size_t)(n0 + srow + 64) * Kdim + k0 + schunk * 8);
        __syncthreads();
        ((uint4*)lA)[srow * 4 + schunk] = a0;
        ((uint4*)lA)[(srow + 64) * 4 + schunk] = a1;
        ((uint4*)lB)[srow * 4 + schunk] = b0;
        ((uint4*)lB)[(srow + 64) * 4 + schunk] = b1;
        __syncthreads();
        bf16x8 af[4], bfr[4];
        #pragma unroll
        for (int t = 0; t < 4; ++t) {
            af[t]  = *(const bf16x8*)(lA + (wm * 64 + t * 16 + lm) * 32 + quad * 8);
            bfr[t] = *(const bf16x8*)(lB + (wn * 64 + t * 16 + lm) * 32 + quad * 8);
        }
        #pragma unroll
        for (int mt = 0; mt < 4; ++mt)
            #pragma unroll
            for (int nt = 0; nt < 4; ++nt)
                acc[mt * 4 + nt] = __builtin_amdgcn_mfma_f32_16x16x32_bf16(
                    af[mt], bfr[nt], acc[mt * 4 + nt], 0, 0, 0);
    }

    #pragma unroll
    for (int mt = 0; mt < 4; ++mt) {
        #pragma unroll
        for (int nt = 0; nt < 4; ++nt) {
            f32x4 c = acc[mt * 4 + nt];
            int gn = n0 + wn * 64 + nt * 16 + lm;
            float bv = bias[gn];
            #pragma unroll
            for (int i = 0; i < 4; ++i) {
                int gm = m0 + wm * 64 + mt * 16 + quad * 4 + i;
                float v = c[i] + bv;
                if (EPI == 0) {
                    int h = gn / 384, r = gn - h * 384;
                    int t = r >> 7, d = r & 127;
                    int b = gm >> 11, s = gm & 2047;
                    ushort bb = f2bf(v);
                    if (t == 0) {
                        q_out[((size_t)(b * NHEAD + h) * S_LEN + s) * HSZ + d] = bb;
                    } else if (t == 1) {
                        k_out[((size_t)(b * NHEAD + h) * S_LEN + s) * HSZ + d] = bb;
                    } else {
                        // V stored TRANSPOSED: [bh][d][s]
                        v_out[((size_t)(b * NHEAD + h) * HSZ + d) * S_LEN + s] = bb;
                    }
                } else {
                    Cout[(size_t)gm * Ndim + gn] = v;
                }
            }
        }
    }
}

// ---------------- RoPE in place on dims 0..31 of Q and K ----------------
__global__ void rope_kernel(ushort* __restrict__ Qr, ushort* __restrict__ Kr,
                            const int* __restrict__ pos_ids) {
    int idx = blockIdx.x * 256 + threadIdx.x;   // B*H*S*16 = 1048576
    int j = idx & 15;
    int row = idx >> 4;            // (b*16+h)*2048 + s
    int s = row & 2047;
    int bh = row >> 11;
    int b = bh >> 4;
    int pos = pos_ids[b * S_LEN + s];
    double inv = exp2(-(double)j * (13.287712379549449 / 16.0));
    double th = (double)pos * inv;
    float c = (float)cos(th), sn = (float)sin(th);
    size_t base = (size_t)row * HSZ;
    {
        float x1 = bf2f(Qr[base + j]), x2 = bf2f(Qr[base + j + 16]);
        Qr[base + j]      = f2bf(x1 * c - x2 * sn);
        Qr[base + j + 16] = f2bf(x2 * c + x1 * sn);
    }
    {
        float x1 = bf2f(Kr[base + j]), x2 = bf2f(Kr[base + j + 16]);
        Kr[base + j]      = f2bf(x1 * c - x2 * sn);
        Kr[base + j + 16] = f2bf(x2 * c + x1 * sn);
    }
}

// ---------------- MFMA flash attention ----------------
// Block: 4 waves, 128 q rows of one (b,h). Wave owns 32 q rows.
// K-tile = 32 keys. S^T via mfma(K,Q) -> q = lane&15 cols => per-lane softmax state.
// O^T via mfma(Vt,P) -> O cols = q = lane&15, rows = d => packed ushort4 stores.
__global__ __launch_bounds__(256, 2) void attn_mfma(
    const ushort* __restrict__ Q, const ushort* __restrict__ K,
    const ushort* __restrict__ Vt, ushort* __restrict__ O) {
    __shared__ __align__(16) ushort lQ[128 * 136];  // 34816 B
    __shared__ __align__(16) ushort lK[32 * 136];   //  8704 B
    __shared__ __align__(16) ushort lVt[128 * 40];  // 10240 B
    __shared__ __align__(16) ushort lP[4 * 32 * 40];// 10240 B  (total 64000 B)

    const int tid = threadIdx.x;
    const int wid = tid >> 6, lane = tid & 63;
    const int L = lane & 15, quad = lane >> 4;
    const int bh = blockIdx.y;
    const int q0 = blockIdx.x * 128;
    const int wq0 = wid * 32;
    const size_t base = (size_t)bh * S_LEN * HSZ;
    const uint4* Qg = (const uint4*)(Q + base + (size_t)q0 * HSZ);
    const uint4* Kg = (const uint4*)(K + base);
    const uint4* Vg = (const uint4*)(Vt + base);     // [128][2048]
    ushort* lPw = lP + wid * (32 * 40);

    // stage Q: 128 rows x 128 cols (2048 uint4)
    #pragma unroll
    for (int p = 0; p < 8; ++p) {
        int idx = tid + p * 256;
        int row = idx >> 4, ch = idx & 15;
        uint4 v = Qg[idx];
        *(uint4*)(lQ + row * 136 + ch * 8) = v;
    }
    __syncthreads();

    bf16x8 qf[2][4];
    #pragma unroll
    for (int qs = 0; qs < 2; ++qs)
        #pragma unroll
        for (int dc = 0; dc < 4; ++dc)
            qf[qs][dc] = *(const bf16x8*)(lQ + (wq0 + qs * 16 + L) * 136 + dc * 32 + quad * 8);

    f32x4 acc_o[8][2];
    #pragma unroll
    for (int dt = 0; dt < 8; ++dt)
        #pragma unroll
        for (int qs = 0; qs < 2; ++qs) acc_o[dt][qs] = (f32x4){0.f, 0.f, 0.f, 0.f};
    float mrow[2] = {-1e30f, -1e30f}, lrow[2] = {0.f, 0.f};
    const float scale = 0.08838834764831845f;  // 1/sqrt(128)

    for (int kt = 0; kt < S_LEN / 32; ++kt) {
        __syncthreads();
        #pragma unroll
        for (int p = 0; p < 2; ++p) {
            int idx = tid + p * 256;            // < 512
            int row = idx >> 4, ch = idx & 15;
            uint4 kv = Kg[(kt * 32 + row) * 16 + ch];
            *(uint4*)(lK + row * 136 + ch * 8) = kv;
            int d = idx >> 2, c2 = idx & 3;
            uint4 vv = Vg[d * 256 + kt * 4 + c2];
            *(uint4*)(lVt + d * 40 + c2 * 8) = vv;
        }
        __syncthreads();

        // S^T: rows k (2 subtiles), cols q (2 subtiles of wave's 32)
        f32x4 sa[2][2];
        #pragma unroll
        for (int t = 0; t < 2; ++t)
            #pragma unroll
            for (int qs = 0; qs < 2; ++qs) sa[t][qs] = (f32x4){0.f, 0.f, 0.f, 0.f};
        #pragma unroll
        for (int t = 0; t < 2; ++t)
            #pragma unroll
            for (int dc = 0; dc < 4; ++dc) {
                bf16x8 kf = *(const bf16x8*)(lK + (t * 16 + L) * 136 + dc * 32 + quad * 8);
                sa[t][0] = __builtin_amdgcn_mfma_f32_16x16x32_bf16(kf, qf[0][dc], sa[t][0], 0, 0, 0);
                sa[t][1] = __builtin_amdgcn_mfma_f32_16x16x32_bf16(kf, qf[1][dc], sa[t][1], 0, 0, 0);
            }

        // online softmax; lane's q = qs*16 + L (same for all quads)
        float alpha[2];
        #pragma unroll
        for (int qs = 0; qs < 2; ++qs) {
            float tm = -1e30f;
            #pragma unroll
            for (int t = 0; t < 2; ++t)
                #pragma unroll
                for (int r = 0; r < 4; ++r) {
                    sa[t][qs][r] *= scale;
                    tm = fmaxf(tm, sa[t][qs][r]);
                }
            tm = fmaxf(tm, __shfl_xor(tm, 16));
            tm = fmaxf(tm, __shfl_xor(tm, 32));
            float mn = fmaxf(mrow[qs], tm);
            alpha[qs] = __expf(mrow[qs] - mn);
            float ps = 0.f;
            #pragma unroll
            for (int t = 0; t < 2; ++t)
                #pragma unroll
                for (int r = 0; r < 4; ++r) {
                    float pv = __expf(sa[t][qs][r] - mn);
                    ps += pv;
                    sa[t][qs][r] = pv;
                }
            ps += __shfl_xor(ps, 16);
            ps += __shfl_xor(ps, 32);
            lrow[qs] = lrow[qs] * alpha[qs] + ps;
            mrow[qs] = mn;
        }

        // pack P (bf16) into per-wave LDS: row q (stride 40), 4 consecutive k per lane
        #pragma unroll
        for (int t = 0; t < 2; ++t)
            #pragma unroll
            for (int qs = 0; qs < 2; ++qs) {
                ushort4 u;
                u.x = f2bf(sa[t][qs][0]);
                u.y = f2bf(sa[t][qs][1]);
                u.z = f2bf(sa[t][qs][2]);
                u.w = f2bf(sa[t][qs][3]);
                *(ushort4*)(lPw + (qs * 16 + L) * 40 + t * 16 + quad * 4) = u;
            }
        __asm__ volatile("s_waitcnt lgkmcnt(0)" ::: "memory");

        if (__any(alpha[0] < 1.f || alpha[1] < 1.f)) {
            #pragma unroll
            for (int dt = 0; dt < 8; ++dt)
                #pragma unroll
                for (int qs = 0; qs < 2; ++qs) {
                    acc_o[dt][qs][0] *= alpha[qs];
                    acc_o[dt][qs][1] *= alpha[qs];
                    acc_o[dt][qs][2] *= alpha[qs];
                    acc_o[dt][qs][3] *= alpha[qs];
                }
        }

        bf16x8 pf0 = *(const bf16x8*)(lPw + L * 40 + quad * 8);
        bf16x8 pf1 = *(const bf16x8*)(lPw + (16 + L) * 40 + quad * 8);
        #pragma unroll
        for (int dt = 0; dt < 8; ++dt) {
            bf16x8 vf = *(const bf16x8*)(lVt + (dt * 16 + L) * 40 + quad * 8);
            acc_o[dt][0] = __builtin_amdgcn_mfma_f32_16x16x32_bf16(vf, pf0, acc_o[dt][0], 0, 0, 0);
            acc_o[dt][1] = __builtin_amdgcn_mfma_f32_16x16x32_bf16(vf, pf1, acc_o[dt][1], 0, 0, 0);
        }
    }

    // write O: row = (b, s = q0+wq0+qs*16+L), col = h*128 + dt*16 + quad*4 .. +3
    const int b = bh >> 4, h = bh & 15;
    #pragma unroll
    for (int qs = 0; qs < 2; ++qs) {
        float inv = 1.f / lrow[qs];
        size_t row = ((size_t)(b * S_LEN + q0 + wq0 + qs * 16 + L)) * (NHEAD * HSZ) + h * HSZ;
        #pragma unroll
        for (int dt = 0; dt < 8; ++dt) {
            ushort4 u;
            u.x = f2bf(acc_o[dt][qs][0] * inv);
            u.y = f2bf(acc_o[dt][qs][1] * inv);
            u.z = f2bf(acc_o[dt][qs][2] * inv);
            u.w = f2bf(acc_o[dt][qs][3] * inv);
            *(ushort4*)(O + row + dt * 16 + quad * 4) = u;
        }
    }
}

extern "C" void kernel_launch(void* const* d_in, const int* in_sizes, int n_in,
                              void* d_out, int out_size, void* d_ws, size_t ws_size,
                              hipStream_t stream) {
    const float* hidden = (const float*)d_in[0];
    const int*   pos    = (const int*)d_in[1];
    const float* Wqkv   = (const float*)d_in[2];
    const float* bqkv   = (const float*)d_in[3];
    const float* Wd     = (const float*)d_in[4];
    const float* bd     = (const float*)d_in[5];

    char* ws = (char*)d_ws;
    ushort* hA  = (ushort*)ws;                               // 16 MB (reused as O)
    ushort* WqT = (ushort*)(ws + 16777216ull);               // 24 MB
    ushort* WdT = (ushort*)(ws + 41943040ull);               //  8 MB
    ushort* Qb  = (ushort*)(ws + 50331648ull);               // 16 MB
    ushort* Kb  = (ushort*)(ws + 67108864ull);               // 16 MB
    ushort* Vb  = (ushort*)(ws + 83886080ull);               // 16 MB, V^T [bh][d][s]

    cast_kernel<<<dim3(8192), dim3(256), 0, stream>>>(hidden, hA, 2097152);
    transpose_cast<<<dim3(192, 64), dim3(32, 8), 0, stream>>>(Wqkv, WqT, 2048, 6144);
    transpose_cast<<<dim3(64, 64), dim3(32, 8), 0, stream>>>(Wd, WdT, 2048, 2048);

    gemm128<0><<<dim3(48, 32), dim3(256), 0, stream>>>(hA, WqT, bqkv, nullptr, 2048, 6144,
                                                       Qb, Kb, Vb);
    rope_kernel<<<dim3(4096), dim3(256), 0, stream>>>(Qb, Kb, pos);

    ushort* Obuf = hA;  // hidden bf16 no longer needed
    attn_mfma<<<dim3(16, 32), dim3(256), 0, stream>>>(Qb, Kb, Vb, Obuf);

    gemm128<1><<<dim3(16, 32), dim3(256), 0, stream>>>(Obuf, WdT, bd, (float*)d_out,
                                                       2048, 2048, nullptr, nullptr, nullptr);
}